// Round 4
// baseline (322.071 us; speedup 1.0000x reference)
//
#include <hip/hip_runtime.h>

// RoiPoolingConv: crop_and_resize (bilinear, 14x14 grid) + 2x2 max pool
// fm: (38,50,512) f32; rois: (512,5) f32 [batch, x1, y1, x2, y2]
// out[n,ph,pw,c] = max over (jy,ix in {0,1}) of bilinear sample (2ph+jy, 2pw+ix)
//
// R4: back to R2's per-window block (best measured: max TLP, 50176 waves).
//   + nontemporal stores: 51 MB of streamed output no longer evicts the
//     3.89 MB fm from the 4 MiB per-XCD L2 (fm barely fits).
//   + loads hoisted ahead of all lerps in every (xcs,ycs) case body: all
//     corner loads in flight before the first dependent VALU op.

#define FM_H 38
#define FM_W 50
#define NCH  512
#define NPP  49   // 7*7

__device__ __forceinline__ float4 lerp4(const float4 a, const float4 b, const float w) {
    const float iw = 1.0f - w;
    return make_float4(a.x * iw + b.x * w,
                       a.y * iw + b.y * w,
                       a.z * iw + b.z * w,
                       a.w * iw + b.w * w);
}

__device__ __forceinline__ float4 max4(const float4 a, const float4 b) {
    return make_float4(fmaxf(a.x, b.x), fmaxf(a.y, b.y),
                       fmaxf(a.z, b.z), fmaxf(a.w, b.w));
}

#define LD4(p) (*(const float4*)(p))

__device__ __forceinline__ void st_nt4(float* p, const float4 v) {
    __builtin_nontemporal_store(v.x, p + 0);
    __builtin_nontemporal_store(v.y, p + 1);
    __builtin_nontemporal_store(v.z, p + 2);
    __builtin_nontemporal_store(v.w, p + 3);
}

__global__ __launch_bounds__(128) void roi_pool_kernel(
    const float* __restrict__ fm,
    const float* __restrict__ rois,
    float* __restrict__ out)
{
    const int bi = blockIdx.x;          // n*49 + ph*7 + pw
    const int n  = bi / NPP;
    const int r  = bi - n * NPP;
    const int ph = r / 7;
    const int pw = r - ph * 7;
    const int c  = threadIdx.x * 4;     // 4 channels per thread (float4)

    const float x1 = rois[n * 5 + 1];
    const float y1 = rois[n * 5 + 2];
    const float x2 = rois[n * 5 + 3];
    const float y2 = rois[n * 5 + 4];
    const float SX = 49.0f / 800.0f;    // (W-1)/IM_W
    const float SY = 37.0f / 600.0f;    // (H-1)/IM_H

    // --- x samples: i = 2*pw + {0,1} ---
    int   xA0, xB0, xA1, xB1;
    float wx0, wx1;
    {
        const float t0 = (float)(2 * pw)     * (1.0f / 13.0f);
        const float t1 = (float)(2 * pw + 1) * (1.0f / 13.0f);
        const float dx = x2 - x1;
        const float xx0 = (x1 + t0 * dx) * SX;
        const float xx1 = (x1 + t1 * dx) * SX;
        const float xf0 = floorf(xx0), xf1 = floorf(xx1);
        int a0 = (int)xf0; a0 = min(max(a0, 0), FM_W - 1);
        int a1 = (int)xf1; a1 = min(max(a1, 0), FM_W - 1);
        xA0 = a0; xB0 = min(a0 + 1, FM_W - 1);
        xA1 = a1; xB1 = min(a1 + 1, FM_W - 1);
        wx0 = xx0 - xf0;                 // weights from UNclipped floor
        wx1 = xx1 - xf1;
    }
    // --- y samples: j = 2*ph + {0,1} ---
    int   yA0, yB0, yA1, yB1;
    float wy0, wy1;
    {
        const float t0 = (float)(2 * ph)     * (1.0f / 13.0f);
        const float t1 = (float)(2 * ph + 1) * (1.0f / 13.0f);
        const float dy = y2 - y1;
        const float yy0 = (y1 + t0 * dy) * SY;
        const float yy1 = (y1 + t1 * dy) * SY;
        const float yf0 = floorf(yy0), yf1 = floorf(yy1);
        int a0 = (int)yf0; a0 = min(max(a0, 0), FM_H - 1);
        int a1 = (int)yf1; a1 = min(max(a1, 0), FM_H - 1);
        yA0 = a0; yB0 = min(a0 + 1, FM_H - 1);
        yA1 = a1; yB1 = min(a1 + 1, FM_H - 1);
        wy0 = yy0 - yf0;
        wy1 = yy1 - yf1;
    }

    // Axis cases (block-uniform → scalar branches):
    // 0 = both samples in same cell, 1 = adjacent (share one line), 2 = disjoint.
    const int xcs = (xA1 == xA0) ? 0 : ((xA1 == xB0) ? 1 : 2);
    const int ycs = (yA1 == yA0) ? 0 : ((yA1 == yB0) ? 1 : 2);

    const float* fmc = fm + c;

    // Distinct columns (2..4) and their count; per-sample column slots.
    int cols[4];
    int nc;
    if (xcs == 0)      { cols[0]=xA0; cols[1]=xB0; nc = 2; }
    else if (xcs == 1) { cols[0]=xA0; cols[1]=xB0; cols[2]=xB1; nc = 3; }
    else               { cols[0]=xA0; cols[1]=xB0; cols[2]=xA1; cols[3]=xB1; nc = 4; }
    // sample0 uses cols[0],cols[1]; sample1 uses cols[s1a],cols[s1a+1]
    const int s1a = (xcs == 0) ? 0 : ((xcs == 1) ? 1 : 2);

    // Distinct rows (2..4).
    int rows[4];
    int nr;
    if (ycs == 0)      { rows[0]=yA0; rows[1]=yB0; nr = 2; }
    else if (ycs == 1) { rows[0]=yA0; rows[1]=yB0; rows[2]=yB1; nr = 3; }
    else               { rows[0]=yA0; rows[1]=yB0; rows[2]=yA1; rows[3]=yB1; nr = 4; }
    const int r1a = (ycs == 0) ? 0 : ((ycs == 1) ? 1 : 2);

    // ---- Load ALL distinct corners first (up to 16), then do all math. ----
    // v[row][col]
    float4 v[4][4];
#pragma unroll
    for (int rr = 0; rr < 4; ++rr) {
        if (rr < nr) {
            const float* bp = fmc + (size_t)rows[rr] * (FM_W * NCH);
#pragma unroll
            for (int cc = 0; cc < 4; ++cc) {
                if (cc < nc) v[rr][cc] = LD4(bp + cols[cc] * NCH);
            }
        }
    }

    // x-interpolate every loaded row at both samples.
    float4 t0[4], t1[4];
#pragma unroll
    for (int rr = 0; rr < 4; ++rr) {
        if (rr < nr) {
            t0[rr] = lerp4(v[rr][0],     v[rr][1],       wx0);
            t1[rr] = lerp4(v[rr][s1a],   v[rr][s1a + 1], wx1);
        }
    }

    // y-interpolate: sample rows (0,1) for jy=0 and (r1a, r1a+1) for jy=1.
    const float4 s00 = lerp4(t0[0],       t0[1],         wy0);
    const float4 s01 = lerp4(t1[0],       t1[1],         wy0);
    const float4 s10 = lerp4(t0[r1a],     t0[r1a + 1],   wy1);
    const float4 s11 = lerp4(t1[r1a],     t1[r1a + 1],   wy1);
    const float4 best = max4(max4(s00, s01), max4(s10, s11));

    st_nt4(out + (size_t)bi * NCH + c, best);
}

extern "C" void kernel_launch(void* const* d_in, const int* in_sizes, int n_in,
                              void* d_out, int out_size, void* d_ws, size_t ws_size,
                              hipStream_t stream) {
    const float* fm   = (const float*)d_in[0];   // (1,38,50,512) f32
    const float* rois = (const float*)d_in[1];   // (512,5) f32
    float* out = (float*)d_out;                  // (1,512,7,7,512) f32

    const int N = in_sizes[1] / 5;               // 512 rois
    const int blocks = N * NPP;                  // one block per (roi, ph, pw)
    roi_pool_kernel<<<blocks, NCH / 4, 0, stream>>>(fm, rois, out);
}

// Round 6
// 88.148 us; speedup vs baseline: 3.6538x; 3.6538x over previous
//
#include <hip/hip_runtime.h>

// RoiPoolingConv: crop_and_resize (bilinear, 14x14 grid) + 2x2 max pool
// fm: (38,50,512) f32; rois: (512,5) f32 [batch, x1, y1, x2, y2]
// out[n,ph,pw,c] = max over (jy,ix in {0,1}) of bilinear sample (2ph+jy, 2pw+ix)
//
// R6 = R5 with the nt store fixed: __builtin_nontemporal_store needs a native
// clang vector type, not HIP_vector_type — bit-cast float4 -> ext_vector_type(4)
// and store through that (emits one global_store_dwordx4 ... nt; full-line,
// no partial-line RMW like R4's scalarized version).

#define FM_H 38
#define FM_W 50
#define NCH  512
#define NPP  49   // 7*7

typedef float v4f __attribute__((ext_vector_type(4)));

__device__ __forceinline__ float4 lerp4(const float4 a, const float4 b, const float w) {
    const float iw = 1.0f - w;
    return make_float4(a.x * iw + b.x * w,
                       a.y * iw + b.y * w,
                       a.z * iw + b.z * w,
                       a.w * iw + b.w * w);
}

__device__ __forceinline__ float4 max4(const float4 a, const float4 b) {
    return make_float4(fmaxf(a.x, b.x), fmaxf(a.y, b.y),
                       fmaxf(a.z, b.z), fmaxf(a.w, b.w));
}

#define LD4(p) (*(const float4*)(p))

__device__ __forceinline__ void st_nt4(float* p, const float4 v) {
    v4f vv;
    vv.x = v.x; vv.y = v.y; vv.z = v.z; vv.w = v.w;
    __builtin_nontemporal_store(vv, (v4f*)p);
}

__global__ __launch_bounds__(128) void roi_pool_kernel(
    const float* __restrict__ fm,
    const float* __restrict__ rois,
    float* __restrict__ out)
{
    const int bi = blockIdx.x;          // n*49 + ph*7 + pw
    const int n  = bi / NPP;
    const int r  = bi - n * NPP;
    const int ph = r / 7;
    const int pw = r - ph * 7;
    const int c  = threadIdx.x * 4;     // 4 channels per thread (float4)

    // ROI box (block-uniform). Combined scale: (v/IM) * (dim-1).
    const float x1 = rois[n * 5 + 1];
    const float y1 = rois[n * 5 + 2];
    const float x2 = rois[n * 5 + 3];
    const float y2 = rois[n * 5 + 4];
    const float SX = 49.0f / 800.0f;    // (W-1)/IM_W
    const float SY = 37.0f / 600.0f;    // (H-1)/IM_H

    // --- x samples: i = 2*pw + {0,1} ---
    int   xA0, xB0, xA1, xB1;
    float wx0, wx1;
    {
        const float t0 = (float)(2 * pw)     * (1.0f / 13.0f);
        const float t1 = (float)(2 * pw + 1) * (1.0f / 13.0f);
        const float dx = x2 - x1;
        const float xx0 = (x1 + t0 * dx) * SX;
        const float xx1 = (x1 + t1 * dx) * SX;
        const float xf0 = floorf(xx0), xf1 = floorf(xx1);
        int a0 = (int)xf0; a0 = min(max(a0, 0), FM_W - 1);
        int a1 = (int)xf1; a1 = min(max(a1, 0), FM_W - 1);
        xA0 = a0; xB0 = min(a0 + 1, FM_W - 1);
        xA1 = a1; xB1 = min(a1 + 1, FM_W - 1);
        wx0 = xx0 - xf0;                 // weights from UNclipped floor
        wx1 = xx1 - xf1;
    }
    // --- y samples: j = 2*ph + {0,1} ---
    int   yA0, yB0, yA1, yB1;
    float wy0, wy1;
    {
        const float t0 = (float)(2 * ph)     * (1.0f / 13.0f);
        const float t1 = (float)(2 * ph + 1) * (1.0f / 13.0f);
        const float dy = y2 - y1;
        const float yy0 = (y1 + t0 * dy) * SY;
        const float yy1 = (y1 + t1 * dy) * SY;
        const float yf0 = floorf(yy0), yf1 = floorf(yy1);
        int a0 = (int)yf0; a0 = min(max(a0, 0), FM_H - 1);
        int a1 = (int)yf1; a1 = min(max(a1, 0), FM_H - 1);
        yA0 = a0; yB0 = min(a0 + 1, FM_H - 1);
        yA1 = a1; yB1 = min(a1 + 1, FM_H - 1);
        wy0 = yy0 - yf0;
        wy1 = yy1 - yf1;
    }

    // Case per axis (block-uniform): 0 = same cell, 1 = adjacent (share one
    // corner), 2 = disjoint. Note xA1==xA0 implies xB1==xB0.
    const int xcs = (xA1 == xA0) ? 0 : ((xA1 == xB0) ? 1 : 2);
    const int ycs = (yA1 == yA0) ? 0 : ((yA1 == yB0) ? 1 : 2);

    const float* fmc = fm + c;

    // x-interpolate one fm row at both sample columns, with col dedup.
    auto interpX = [&](int row, float4& t0, float4& t1) {
        const float* bp = fmc + (size_t)row * (FM_W * NCH);
        if (xcs == 0) {
            const float4 v0 = LD4(bp + xA0 * NCH);
            const float4 v1 = LD4(bp + xB0 * NCH);
            t0 = lerp4(v0, v1, wx0);
            t1 = lerp4(v0, v1, wx1);
        } else if (xcs == 1) {
            const float4 v0 = LD4(bp + xA0 * NCH);
            const float4 v1 = LD4(bp + xB0 * NCH);   // == xA1
            const float4 v2 = LD4(bp + xB1 * NCH);
            t0 = lerp4(v0, v1, wx0);
            t1 = lerp4(v1, v2, wx1);
        } else {
            const float4 v0 = LD4(bp + xA0 * NCH);
            const float4 v1 = LD4(bp + xB0 * NCH);
            const float4 v2 = LD4(bp + xA1 * NCH);
            const float4 v3 = LD4(bp + xB1 * NCH);
            t0 = lerp4(v0, v1, wx0);
            t1 = lerp4(v2, v3, wx1);
        }
    };

    float4 best;
    if (ycs == 0) {
        // rows {yA0, yB0}; both y-samples use the same row pair
        float4 a0, a1, b0, b1;
        interpX(yA0, a0, a1);
        interpX(yB0, b0, b1);
        const float4 s00 = lerp4(a0, b0, wy0);
        const float4 s01 = lerp4(a1, b1, wy0);
        const float4 s10 = lerp4(a0, b0, wy1);
        const float4 s11 = lerp4(a1, b1, wy1);
        best = max4(max4(s00, s01), max4(s10, s11));
    } else if (ycs == 1) {
        // rows {yA0, yB0==yA1, yB1}
        float4 a0, a1, b0, b1, e0, e1;
        interpX(yA0, a0, a1);
        interpX(yB0, b0, b1);
        interpX(yB1, e0, e1);
        const float4 s00 = lerp4(a0, b0, wy0);
        const float4 s01 = lerp4(a1, b1, wy0);
        const float4 s10 = lerp4(b0, e0, wy1);
        const float4 s11 = lerp4(b1, e1, wy1);
        best = max4(max4(s00, s01), max4(s10, s11));
    } else {
        // 4 distinct rows
        float4 a0, a1, b0, b1, d0, d1, e0, e1;
        interpX(yA0, a0, a1);
        interpX(yB0, b0, b1);
        interpX(yA1, d0, d1);
        interpX(yB1, e0, e1);
        const float4 s00 = lerp4(a0, b0, wy0);
        const float4 s01 = lerp4(a1, b1, wy0);
        const float4 s10 = lerp4(d0, e0, wy1);
        const float4 s11 = lerp4(d1, e1, wy1);
        best = max4(max4(s00, s01), max4(s10, s11));
    }

    // Full-line vector non-temporal store: 64 lanes x 16 B = 1024 B contiguous.
    st_nt4(out + (size_t)bi * NCH + c, best);
}

extern "C" void kernel_launch(void* const* d_in, const int* in_sizes, int n_in,
                              void* d_out, int out_size, void* d_ws, size_t ws_size,
                              hipStream_t stream) {
    const float* fm   = (const float*)d_in[0];   // (1,38,50,512) f32
    const float* rois = (const float*)d_in[1];   // (512,5) f32
    float* out = (float*)d_out;                  // (1,512,7,7,512) f32

    const int N = in_sizes[1] / 5;               // 512 rois
    const int blocks = N * NPP;                  // one block per (roi, ph, pw)
    roi_pool_kernel<<<blocks, NCH / 4, 0, stream>>>(fm, rois, out);
}